// Round 8
// baseline (691.231 us; speedup 1.0000x reference)
//
#include <hip/hip_runtime.h>
#include <hip/hip_bf16.h>
#include <hip/hip_fp16.h>

#define NLAYERS 4
#define GRID_STRIDE 2048
#define NB 32          // nodes per edge_layer block
#define CAP 256        // LDS-resident edges per block (mean load; overflow -> global fallback)

typedef _Float16 half8_t __attribute__((ext_vector_type(8)));
typedef float float4_t __attribute__((ext_vector_type(4)));
typedef float float8_t __attribute__((ext_vector_type(8)));
typedef unsigned uint2_t __attribute__((ext_vector_type(2)));

// Global hidden-dim permutation: column pair (j, j+16) lives at positions (2j, 2j+1).
// All hidden-state arrays are POSITION space; weight-row / bias / bn-param lookups are
// permuted at load time.
__device__ __forceinline__ int permcol(int pos) { return (pos >> 1) | ((pos & 1) << 4); }

__device__ __forceinline__ void unp4v(uint2_t r, float* f)
{
    unsigned lo = r.x, hi = r.y;
    float2 a = __half22float2(*(__half2*)&lo);
    float2 b = __half22float2(*(__half2*)&hi);
    f[0] = a.x; f[1] = a.y; f[2] = b.x; f[3] = b.y;
}

__device__ __forceinline__ float fast_sigmoid(float x)
{
    return __builtin_amdgcn_rcpf(1.f + __expf(-x));
}

// ---------------- small zero kernel ----------------
__global__ void zero_ints(int* __restrict__ p, int n)
{
    int i = blockIdx.x * 256 + threadIdx.x;
    if (i < n) p[i] = 0;
}

// ---------------- CSR build ----------------
__global__ void hist_kernel(const int* __restrict__ dsts, int* __restrict__ counts, int E)
{
    int i = blockIdx.x * 256 + threadIdx.x;
    if (i < E) atomicAdd(&counts[dsts[i]], 1);
}

__global__ __launch_bounds__(256) void scan1(const int* __restrict__ counts,
                                             int* __restrict__ offsets,
                                             int* __restrict__ blocksums, int N)
{
    __shared__ int sdata[256];
    int t = threadIdx.x;
    int bbase = blockIdx.x * 1024;
    int v[4]; int s = 0;
#pragma unroll
    for (int q = 0; q < 4; q++) {
        int idx = bbase + t * 4 + q;
        v[q] = (idx < N) ? counts[idx] : 0;
        s += v[q];
    }
    sdata[t] = s;
    __syncthreads();
    for (int off = 1; off < 256; off <<= 1) {
        int x = (t >= off) ? sdata[t - off] : 0;
        __syncthreads();
        sdata[t] += x;
        __syncthreads();
    }
    int excl = sdata[t] - s;
    int run = excl;
#pragma unroll
    for (int q = 0; q < 4; q++) {
        int idx = bbase + t * 4 + q;
        if (idx < N) offsets[idx] = run;
        run += v[q];
    }
    if (t == 255) blocksums[blockIdx.x] = sdata[255];
}

__global__ void scan2(int* __restrict__ blocksums, int nb)
{
    if (threadIdx.x == 0 && blockIdx.x == 0) {
        int run = 0;
        for (int b = 0; b < nb; b++) { int t = blocksums[b]; blocksums[b] = run; run += t; }
    }
}

__global__ void scan3(int* __restrict__ offsets, const int* __restrict__ blocksums,
                      int* __restrict__ cursor, int N)
{
    int i = blockIdx.x * 256 + threadIdx.x;
    if (i < N) {
        int v = offsets[i] + blocksums[i >> 10];
        offsets[i] = v;
        cursor[i] = v;
    }
}

// scatter: 8 dst-range groups (XCD-affine via blockIdx&7).
__global__ void scatter_perm(const int* __restrict__ dsts, int* __restrict__ cursor,
                             int* __restrict__ perm, int E, int N)
{
    int g = blockIdx.x & 7;
    int lo = (int)((long long)N * g >> 3);
    int hi = (int)((long long)N * (g + 1) >> 3);
    int nbg = gridDim.x >> 3;
    int bg = blockIdx.x >> 3;
    for (int i = bg * 256 + threadIdx.x; i < E; i += nbg * 256) {
        int d = dsts[i];
        if (d >= lo && d < hi) {
            int slot = atomicAdd(&cursor[d], 1);
            perm[slot] = i;
        }
    }
}

__global__ void gather_sd(const int* __restrict__ perm, const int* __restrict__ srcs,
                          const int* __restrict__ dsts, int* __restrict__ srcp,
                          int* __restrict__ dstp, int E)
{
    int i = blockIdx.x * 256 + threadIdx.x;
    if (i < E) {
        int e = perm[i];
        srcp[i] = srcs[e];
        dstp[i] = dsts[e];
    }
}

// ---------------- init projections (write POSITION space) ----------------
__global__ void init_proj4(const float* __restrict__ in, const float* __restrict__ w,
                           const float* __restrict__ b, float4* __restrict__ out, size_t n4)
{
    size_t i = (size_t)blockIdx.x * 256 + threadIdx.x;
    if (i < n4) {
        int j4 = (int)(i & 7) * 4;
        float xv = in[i >> 3];
        int c0 = permcol(j4), c1 = permcol(j4 + 1), c2 = permcol(j4 + 2), c3 = permcol(j4 + 3);
        out[i] = make_float4(fmaf(xv, w[c0], b[c0]), fmaf(xv, w[c1], b[c1]),
                             fmaf(xv, w[c2], b[c2]), fmaf(xv, w[c3], b[c3]));
    }
}

__global__ void init_ep16(const float* __restrict__ e_in, const int* __restrict__ perm,
                          const float* __restrict__ w, const float* __restrict__ b,
                          __half2* __restrict__ out, size_t n4)
{
    size_t i = (size_t)blockIdx.x * 256 + threadIdx.x;
    if (i < n4) {
        int row = (int)(i >> 3);
        float xv = e_in[perm[row]];
        int j4 = (int)(i & 7) * 4;
        int c0 = permcol(j4), c1 = permcol(j4 + 1), c2 = permcol(j4 + 2), c3 = permcol(j4 + 3);
        out[i * 2]     = __floats2half2_rn(fmaf(xv, w[c0], b[c0]), fmaf(xv, w[c1], b[c1]));
        out[i * 2 + 1] = __floats2half2_rn(fmaf(xv, w[c2], b[c2]), fmaf(xv, w[c3], b[c3]));
    }
}

// ---- node GEMMs (MFMA): 16-node tile per wave; weight rows permuted; outputs pairwise.
// Uh now stored fp16 (dedicated buffer) -- it is only the aggregation base.
template <int FUSE>
__global__ __launch_bounds__(256) void node_gemm(
    float* __restrict__ h, const float* __restrict__ hnew_in,
    const float* __restrict__ sc_h, const float* __restrict__ sh_h,
    const float* __restrict__ Aw, const float* __restrict__ Ab,
    const float* __restrict__ Bw, const float* __restrict__ Bb,
    const float* __restrict__ Uw, const float* __restrict__ Ub,
    const float* __restrict__ Vw, const float* __restrict__ Vb,
    __half* __restrict__ Ahh, __half* __restrict__ Bhh,
    __half* __restrict__ Uhh, __half* __restrict__ Vhh, int N)
{
    int tid = threadIdx.x;
    int lane = tid & 63;
    int m = lane & 15, q = lane >> 4;
    half8_t bA0, bA1, bB0, bB1, bU0, bU1, bV0, bV1;
    float scq[8], shq[8];
#pragma unroll
    for (int i = 0; i < 8; i++) {
        int k = q * 8 + i;       // position index
        int kr = permcol(k);     // original weight row
        bA0[i] = (_Float16)Aw[kr * 32 + m];  bA1[i] = (_Float16)Aw[kr * 32 + m + 16];
        bB0[i] = (_Float16)Bw[kr * 32 + m];  bB1[i] = (_Float16)Bw[kr * 32 + m + 16];
        bU0[i] = (_Float16)Uw[kr * 32 + m];  bU1[i] = (_Float16)Uw[kr * 32 + m + 16];
        bV0[i] = (_Float16)Vw[kr * 32 + m];  bV1[i] = (_Float16)Vw[kr * 32 + m + 16];
        if (FUSE) { scq[i] = sc_h[k]; shq[i] = sh_h[k]; }   // position-indexed stats
    }
    float ab0 = Ab[m], ab1 = Ab[m + 16];
    float bb0 = Bb[m], bb1 = Bb[m + 16];
    float ub0 = Ub[m], ub1 = Ub[m + 16];
    float vb0 = Vb[m], vb1 = Vb[m + 16];

    int ntile = (N + 15) >> 4;
    int wid = blockIdx.x * 4 + (tid >> 6);
    int nwave = gridDim.x * 4;
    for (int t = wid; t < ntile; t += nwave) {
        int base = t << 4;
        int arow = base + m;
        bool valid = arow < N;
        if (!valid) arow = N - 1;
        float8_t hv = *(const float8_t*)(h + (size_t)arow * 32 + q * 8);
        if (FUSE) {
            float8_t pv = *(const float8_t*)(hnew_in + (size_t)arow * 32 + q * 8);
#pragma unroll
            for (int i = 0; i < 8; i++)
                hv[i] += fmaxf(fmaf(pv[i], scq[i], shq[i]), 0.f);
            if (valid) *(float8_t*)(h + (size_t)arow * 32 + q * 8) = hv;
        }
        half8_t a;
#pragma unroll
        for (int i = 0; i < 8; i++) a[i] = (_Float16)hv[i];
        float4_t aA0 = __builtin_amdgcn_mfma_f32_16x16x32_f16(a, bA0, (float4_t){0,0,0,0}, 0, 0, 0);
        float4_t aA1 = __builtin_amdgcn_mfma_f32_16x16x32_f16(a, bA1, (float4_t){0,0,0,0}, 0, 0, 0);
        float4_t aB0 = __builtin_amdgcn_mfma_f32_16x16x32_f16(a, bB0, (float4_t){0,0,0,0}, 0, 0, 0);
        float4_t aB1 = __builtin_amdgcn_mfma_f32_16x16x32_f16(a, bB1, (float4_t){0,0,0,0}, 0, 0, 0);
        float4_t aU0 = __builtin_amdgcn_mfma_f32_16x16x32_f16(a, bU0, (float4_t){0,0,0,0}, 0, 0, 0);
        float4_t aU1 = __builtin_amdgcn_mfma_f32_16x16x32_f16(a, bU1, (float4_t){0,0,0,0}, 0, 0, 0);
        float4_t aV0 = __builtin_amdgcn_mfma_f32_16x16x32_f16(a, bV0, (float4_t){0,0,0,0}, 0, 0, 0);
        float4_t aV1 = __builtin_amdgcn_mfma_f32_16x16x32_f16(a, bV1, (float4_t){0,0,0,0}, 0, 0, 0);
#pragma unroll
        for (int reg = 0; reg < 4; reg++) {
            int node = base + q * 4 + reg;
            if (node < N) {
                size_t o = (size_t)node * 32;
                *(__half2*)(Ahh + o + 2 * m) = __floats2half2_rn(aA0[reg] + ab0, aA1[reg] + ab1);
                *(__half2*)(Bhh + o + 2 * m) = __floats2half2_rn(aB0[reg] + bb0, aB1[reg] + bb1);
                *(__half2*)(Vhh + o + 2 * m) = __floats2half2_rn(aV0[reg] + vb0, aV1[reg] + vb1);
                *(__half2*)(Uhh + o + 2 * m) = __floats2half2_rn(aU0[reg] + ub0, aU1[reg] + ub1);
            }
        }
    }
}

// ---- fused per-layer edge kernel: block owns NB consecutive nodes => a contiguous
// dst-sorted edge range [e0,e1). Phase 1: MFMA en-compute over 16-edge tiles (with
// deferred e-apply), en + src staged in LDS (global enh still written for next layer).
// Phase 2: per-node gated aggregation straight from LDS. e-stats & h-stats emitted.
template <int FIRST>
__global__ __launch_bounds__(256) void edge_layer(
    __half* __restrict__ ep, __half* __restrict__ enh,
    const int* __restrict__ srcp, const int* __restrict__ dstp,
    const int* __restrict__ offsets, const int* __restrict__ counts,
    const __half* __restrict__ Ah, const __half* __restrict__ Bh,
    const __half* __restrict__ Vh, const __half* __restrict__ Uh,
    float* __restrict__ hnew,
    const float* __restrict__ Cw, const float* __restrict__ Cb,
    const float* __restrict__ sc_e, const float* __restrict__ sh_e,
    float* __restrict__ partial_e, float* __restrict__ partial_h,
    int N, int E)
{
    __shared__ __half en_lds[CAP * 32];   // 16384 B
    __shared__ int src_lds[CAP];          // 1024 B
    __shared__ float red[512];            // 2048 B  -> 19456 B total

    int tid = threadIdx.x;
    int lane = tid & 63;
    int m = lane & 15, q = lane >> 4;

    int n0 = blockIdx.x * NB;
    int n1 = n0 + NB; if (n1 > N) n1 = N;
    int e0 = offsets[n0];
    int e1 = (n1 < N) ? offsets[n1] : E;

    // ---------------- phase 1: en compute ----------------
    half8_t b0, b1;
    float sca[8], sha[8];
#pragma unroll
    for (int i = 0; i < 8; i++) {
        int k = q * 8 + i;
        int kr = permcol(k);
        b0[i] = (_Float16)Cw[kr * 32 + m];
        b1[i] = (_Float16)Cw[kr * 32 + m + 16];
        if (!FIRST) { sca[i] = sc_e[k]; sha[i] = sh_e[k]; }
    }
    float cb0 = Cb[m], cb1 = Cb[m + 16];
    float es0 = 0.f, eq0 = 0.f, es1 = 0.f, eq1 = 0.f;

    int len = e1 - e0;
    int T = (len + 15) >> 4;
    int w = tid >> 6;
    for (int t = w; t < T; t += 4) {
        int eb = e0 + (t << 4);
        int arow = eb + m;
        bool avalid = arow < e1;
        int ar = avalid ? arow : e1 - 1;
        half8_t a = *(const half8_t*)(ep + (size_t)ar * 32 + q * 8);
        if (!FIRST) {
            half8_t enp = *(const half8_t*)(enh + (size_t)ar * 32 + q * 8);
#pragma unroll
            for (int i = 0; i < 8; i++) {
                float ev = (float)a[i] + fmaxf(fmaf((float)enp[i], sca[i], sha[i]), 0.f);
                a[i] = (_Float16)ev;
            }
            if (avalid) *(half8_t*)(ep + (size_t)ar * 32 + q * 8) = a;
        }
        float4_t acc0 = __builtin_amdgcn_mfma_f32_16x16x32_f16(a, b0, (float4_t){0.f,0.f,0.f,0.f}, 0, 0, 0);
        float4_t acc1 = __builtin_amdgcn_mfma_f32_16x16x32_f16(a, b1, (float4_t){0.f,0.f,0.f,0.f}, 0, 0, 0);
#pragma unroll
        for (int reg = 0; reg < 4; reg++) {
            int edge = eb + q * 4 + reg;
            if (edge < e1) {
                int s = srcp[edge], d = dstp[edge];
                float2 ah = __half22float2(*(const __half2*)(Ah + (size_t)d * 32 + 2 * m));
                float2 bh = __half22float2(*(const __half2*)(Bh + (size_t)s * 32 + 2 * m));
                float en0 = acc0[reg] + cb0 + ah.x + bh.x;
                float en1 = acc1[reg] + cb1 + ah.y + bh.y;
                __half2 env = __floats2half2_rn(en0, en1);
                *(__half2*)(enh + (size_t)edge * 32 + 2 * m) = env;
                int le = edge - e0;
                if (le < CAP) {
                    *(__half2*)(en_lds + le * 32 + 2 * m) = env;
                    if (m == 0) src_lds[le] = s;
                }
                es0 += en0; eq0 += en0 * en0;
                es1 += en1; eq1 += en1 * en1;
            }
        }
    }

    // e-stats reduction by POSITION (es0 -> pos 2m, es1 -> pos 2m+1)
    float* pe = partial_e + (size_t)blockIdx.x * 64;
    __syncthreads();
    red[tid] = es0;
    __syncthreads();
    if (tid < 16) {
        float s = 0.f;
#pragma unroll
        for (int ww = 0; ww < 4; ww++)
#pragma unroll
            for (int k = 0; k < 4; k++) s += red[ww * 64 + k * 16 + tid];
        pe[2 * tid] = s;
    }
    __syncthreads();
    red[tid] = es1;
    __syncthreads();
    if (tid < 16) {
        float s = 0.f;
#pragma unroll
        for (int ww = 0; ww < 4; ww++)
#pragma unroll
            for (int k = 0; k < 4; k++) s += red[ww * 64 + k * 16 + tid];
        pe[2 * tid + 1] = s;
    }
    __syncthreads();
    red[tid] = eq0;
    __syncthreads();
    if (tid < 16) {
        float s = 0.f;
#pragma unroll
        for (int ww = 0; ww < 4; ww++)
#pragma unroll
            for (int k = 0; k < 4; k++) s += red[ww * 64 + k * 16 + tid];
        pe[32 + 2 * tid] = s;
    }
    __syncthreads();
    red[tid] = eq1;
    __syncthreads();
    if (tid < 16) {
        float s = 0.f;
#pragma unroll
        for (int ww = 0; ww < 4; ww++)
#pragma unroll
            for (int k = 0; k < 4; k++) s += red[ww * 64 + k * 16 + tid];
        pe[32 + 2 * tid + 1] = s;
    }

    // ---------------- phase 2: per-node aggregation from LDS ----------------
    int u = tid & 7, grp = tid >> 3;      // 32 groups of 8 lanes; 1 node each
    int c0 = 4 * u;                       // positions c0..c0+3
    float hs[4] = {0.f, 0.f, 0.f, 0.f}, hq[4] = {0.f, 0.f, 0.f, 0.f};

    int n = n0 + grp;
    if (n < N) {
        int start = offsets[n], lenn = counts[n];
        int lb = start - e0;
        int inl = CAP - lb; if (inl < 0) inl = 0; if (inl > lenn) inl = lenn;
        float num[4] = {0.f, 0.f, 0.f, 0.f}, den[4] = {0.f, 0.f, 0.f, 0.f};
        int qq = 0;
        for (; qq + 2 <= inl; qq += 2) {
            int le0 = lb + qq, le1 = le0 + 1;
            int s0 = src_lds[le0], s1 = src_lds[le1];
            uint2_t enr0 = *(const uint2_t*)(en_lds + le0 * 32 + c0);
            uint2_t enr1 = *(const uint2_t*)(en_lds + le1 * 32 + c0);
            uint2_t vhr0 = *(const uint2_t*)(Vh + (size_t)s0 * 32 + c0);
            uint2_t vhr1 = *(const uint2_t*)(Vh + (size_t)s1 * 32 + c0);
            float en0[4], en1[4], vh0[4], vh1[4];
            unp4v(enr0, en0); unp4v(enr1, en1);
            unp4v(vhr0, vh0); unp4v(vhr1, vh1);
#pragma unroll
            for (int k = 0; k < 4; k++) {
                float sg0 = fast_sigmoid(en0[k]);
                float sg1 = fast_sigmoid(en1[k]);
                num[k] = fmaf(sg0, vh0[k], num[k]);
                num[k] = fmaf(sg1, vh1[k], num[k]);
                den[k] += sg0 + sg1;
            }
        }
        if (qq < inl) {
            int le0 = lb + qq;
            int s0 = src_lds[le0];
            uint2_t enr0 = *(const uint2_t*)(en_lds + le0 * 32 + c0);
            uint2_t vhr0 = *(const uint2_t*)(Vh + (size_t)s0 * 32 + c0);
            float en0[4], vh0[4];
            unp4v(enr0, en0); unp4v(vhr0, vh0);
#pragma unroll
            for (int k = 0; k < 4; k++) {
                float sg0 = fast_sigmoid(en0[k]);
                num[k] = fmaf(sg0, vh0[k], num[k]);
                den[k] += sg0;
            }
            qq++;
        }
        for (; qq < lenn; qq++) {         // overflow fallback (rare; ~2.5% of edges)
            int ge = start + qq;
            int s0 = srcp[ge];
            uint2_t enr0 = *(const uint2_t*)(enh + (size_t)ge * 32 + c0);
            uint2_t vhr0 = *(const uint2_t*)(Vh + (size_t)s0 * 32 + c0);
            float en0[4], vh0[4];
            unp4v(enr0, en0); unp4v(vhr0, vh0);
#pragma unroll
            for (int k = 0; k < 4; k++) {
                float sg0 = fast_sigmoid(en0[k]);
                num[k] = fmaf(sg0, vh0[k], num[k]);
                den[k] += sg0;
            }
        }
        size_t ho = (size_t)n * 32 + c0;
        uint2_t uhr = *(const uint2_t*)(Uh + ho);
        float uh[4];
        unp4v(uhr, uh);
        float hv[4];
#pragma unroll
        for (int k = 0; k < 4; k++)
            hv[k] = uh[k] + num[k] * __builtin_amdgcn_rcpf(den[k] + 1e-6f);
        *(float4*)(hnew + ho) = make_float4(hv[0], hv[1], hv[2], hv[3]);
#pragma unroll
        for (int k = 0; k < 4; k++) { hs[k] += hv[k]; hq[k] += hv[k] * hv[k]; }
    }

    // h-stats reduction
    float* ph = partial_h + (size_t)blockIdx.x * 64;
#pragma unroll
    for (int k = 0; k < 4; k++) {
        __syncthreads();
        red[tid] = hs[k]; red[256 + tid] = hq[k];
        __syncthreads();
        if (tid < 8) {
            float s = 0.f;
#pragma unroll
            for (int g = 0; g < 32; g++) s += red[g * 8 + tid];
            ph[4 * tid + k] = s;
        } else if (tid < 16) {
            int uu = tid - 8;
            float s = 0.f;
#pragma unroll
            for (int g = 0; g < 32; g++) s += red[256 + g * 8 + uu];
            ph[32 + 4 * uu + k] = s;
        }
    }
}

// ---- finalize BN stats BOTH sides in one launch: 64 blocks (0-31 e, 32-63 h) ----
__global__ __launch_bounds__(256) void stats_both(
    const float* __restrict__ pe, const float* __restrict__ ph, int nrows,
    double cntE, double cntN,
    const float* __restrict__ eg, const float* __restrict__ eb,
    const float* __restrict__ hg, const float* __restrict__ hb,
    float* __restrict__ stats)
{
    int j = blockIdx.x;
    int side = j >> 5, jj = j & 31;           // side 0 = e, 1 = h; jj = position
    int col = (jj >> 1) | ((jj & 1) << 4);    // original column for g/b lookup
    const float* partial = side ? ph : pe;
    __shared__ double rs[256], rq[256];
    double s = 0.0, q = 0.0;
    for (int r = threadIdx.x; r < nrows; r += 256) {
        s += (double)partial[(size_t)r * 64 + jj];
        q += (double)partial[(size_t)r * 64 + 32 + jj];
    }
    rs[threadIdx.x] = s; rq[threadIdx.x] = q;
    __syncthreads();
    for (int off = 128; off; off >>= 1) {
        if (threadIdx.x < off) { rs[threadIdx.x] += rs[threadIdx.x + off]; rq[threadIdx.x] += rq[threadIdx.x + off]; }
        __syncthreads();
    }
    if (threadIdx.x == 0) {
        double cnt = side ? cntN : cntE;
        double mean = rs[0] / cnt;
        double var = rq[0] / cnt - mean * mean;
        const float* g = side ? hg : eg;
        const float* b = side ? hb : eb;
        float scale = g[col] * (float)(1.0 / sqrt(var + 1e-5));
        int off2 = side ? 0 : 64;   // h -> stats[0/32], e -> stats[64/96]
        stats[off2 + jj] = scale;
        stats[off2 + 32 + jj] = b[col] - (float)mean * scale;
    }
}

// ---- final h apply: h16 = fp16(h + relu(hnew*sc+sh)) ----
__global__ void apply4_h16(const float4* __restrict__ pre, const float* __restrict__ scale,
                           const float* __restrict__ shift, const float4* __restrict__ hold,
                           __half2* __restrict__ h16, size_t n4)
{
    size_t i = (size_t)blockIdx.x * 256 + threadIdx.x;
    if (i < n4) {
        int j4 = (int)(i & 7) * 4;
        float4 sc = *(const float4*)(scale + j4);
        float4 sh = *(const float4*)(shift + j4);
        float4 p = pre[i], a = hold[i];
        a.x += fmaxf(fmaf(p.x, sc.x, sh.x), 0.f);
        a.y += fmaxf(fmaf(p.y, sc.y, sh.y), 0.f);
        a.z += fmaxf(fmaf(p.z, sc.z, sh.z), 0.f);
        a.w += fmaxf(fmaf(p.w, sc.w, sh.w), 0.f);
        h16[i * 2]     = __floats2half2_rn(a.x, a.y);
        h16[i * 2 + 1] = __floats2half2_rn(a.z, a.w);
    }
}

// ---- predictor (MFMA), PERM edge order; fuses the deferred layer-3 e-apply ----
__global__ __launch_bounds__(256) void predictor(
    const __half* __restrict__ h16, const __half* __restrict__ ep,
    const __half* __restrict__ enh,
    const int* __restrict__ srcp, const int* __restrict__ dstp, const int* __restrict__ perm,
    const float* __restrict__ sc_e, const float* __restrict__ sh_e,
    const float* __restrict__ W1, const float* __restrict__ b1,
    const float* __restrict__ W2, const float* __restrict__ b2v,
    float* __restrict__ out, int E)
{
    int tid = threadIdx.x;
    int lane = tid & 63;
    int m = lane & 15, q = lane >> 4;
    half8_t bf00, bf01, bf10, bf11, bf20, bf21;
    float scq[8], shq[8];
#pragma unroll
    for (int i = 0; i < 8; i++) {
        int k = q * 8 + i;
        int kr = permcol(k);
        bf00[i] = (_Float16)W1[kr * 32 + m];
        bf01[i] = (_Float16)W1[kr * 32 + m + 16];
        bf10[i] = (_Float16)W1[(32 + kr) * 32 + m];
        bf11[i] = (_Float16)W1[(32 + kr) * 32 + m + 16];
        bf20[i] = (_Float16)W1[(64 + kr) * 32 + m];
        bf21[i] = (_Float16)W1[(64 + kr) * 32 + m + 16];
        scq[i] = sc_e[k]; shq[i] = sh_e[k];
    }
    float b10 = b1[m], b11 = b1[m + 16];
    float w20 = W2[m], w21 = W2[m + 16];
    float b2 = b2v[0];

    int ntile = (E + 15) >> 4;
    int wid = blockIdx.x * 4 + (tid >> 6);
    int nwave = gridDim.x * 4;
    for (int t = wid; t < ntile; t += nwave) {
        int base = t << 4;
        int arow = base + m;
        if (arow >= E) arow = E - 1;
        int s = srcp[arow], d = dstp[arow];
        half8_t a0 = *(const half8_t*)(h16 + (size_t)s * 32 + q * 8);
        half8_t a1 = *(const half8_t*)(h16 + (size_t)d * 32 + q * 8);
        half8_t ee = *(const half8_t*)(ep + (size_t)arow * 32 + q * 8);
        half8_t enr = *(const half8_t*)(enh + (size_t)arow * 32 + q * 8);
        half8_t a2;
#pragma unroll
        for (int i = 0; i < 8; i++) {
            float evv = (float)ee[i] + fmaxf(fmaf((float)enr[i], scq[i], shq[i]), 0.f);
            a2[i] = (_Float16)evv;
        }
        float4_t acc0 = {0.f, 0.f, 0.f, 0.f}, acc1 = {0.f, 0.f, 0.f, 0.f};
        acc0 = __builtin_amdgcn_mfma_f32_16x16x32_f16(a0, bf00, acc0, 0, 0, 0);
        acc1 = __builtin_amdgcn_mfma_f32_16x16x32_f16(a0, bf01, acc1, 0, 0, 0);
        acc0 = __builtin_amdgcn_mfma_f32_16x16x32_f16(a1, bf10, acc0, 0, 0, 0);
        acc1 = __builtin_amdgcn_mfma_f32_16x16x32_f16(a1, bf11, acc1, 0, 0, 0);
        acc0 = __builtin_amdgcn_mfma_f32_16x16x32_f16(a2, bf20, acc0, 0, 0, 0);
        acc1 = __builtin_amdgcn_mfma_f32_16x16x32_f16(a2, bf21, acc1, 0, 0, 0);
#pragma unroll
        for (int reg = 0; reg < 4; reg++) {
            float tp = fmaxf(acc0[reg] + b10, 0.f) * w20
                     + fmaxf(acc1[reg] + b11, 0.f) * w21;
            tp += __shfl_xor(tp, 1);
            tp += __shfl_xor(tp, 2);
            tp += __shfl_xor(tp, 4);
            tp += __shfl_xor(tp, 8);
            int idx = base + q * 4 + reg;
            if (m == 0 && idx < E) {
                int oe = perm[idx];
                out[oe] = tp + b2;
            }
        }
    }
}

extern "C" void kernel_launch(void* const* d_in, const int* in_sizes, int n_in,
                              void* d_out, int out_size, void* d_ws, size_t ws_size,
                              hipStream_t stream)
{
    const int N = in_sizes[0];
    const int E = in_sizes[1];

    const float* x    = (const float*)d_in[0];
    const float* e_in = (const float*)d_in[1];
    const int*   eidx = (const int*)d_in[2];
    const float* pe_w = (const float*)d_in[3];
    const float* pe_b = (const float*)d_in[4];
    const float* ed_w = (const float*)d_in[5];
    const float* ed_b = (const float*)d_in[6];
    const float* Aw = (const float*)d_in[7];
    const float* Ab = (const float*)d_in[8];
    const float* Bw = (const float*)d_in[9];
    const float* Bb = (const float*)d_in[10];
    const float* Cw = (const float*)d_in[11];
    const float* Cb = (const float*)d_in[12];
    const float* Uw = (const float*)d_in[13];
    const float* Ub = (const float*)d_in[14];
    const float* Vw = (const float*)d_in[15];
    const float* Vb = (const float*)d_in[16];
    const float* bn_h_g = (const float*)d_in[17];
    const float* bn_h_b = (const float*)d_in[18];
    const float* bn_e_g = (const float*)d_in[19];
    const float* bn_e_b = (const float*)d_in[20];
    const float* W1w = (const float*)d_in[21];
    const float* W1b = (const float*)d_in[22];
    const float* W2w = (const float*)d_in[23];
    const float* W2b = (const float*)d_in[24];

    const int* srcs = eidx;
    const int* dsts = eidx + E;

    size_t nh = (size_t)N * 32;
    size_t eh = (size_t)E * 32;
    int nbE = (N + NB - 1) / NB;    // edge_layer grid

    float* ws = (float*)d_ws;
    float* stats     = ws;                              // 128
    float* partial_e = stats + 128;                     // nbE*64
    float* partial_h = partial_e + (size_t)nbE * 64;    // nbE*64
    float* h    = partial_h + (size_t)nbE * 64;         // nh floats
    float* hnew = h + nh;                               // nh floats (h_new)
    __half* Ah  = (__half*)(hnew + nh);                 // nh halves (h16 at the end)
    __half* Bh  = Ah + nh;                              // nh halves
    __half* Vh  = Bh + nh;                              // nh halves
    __half* Uh  = Vh + nh;                              // nh halves (fp16 Uh)
    __half* ep  = Uh + nh;                              // eh halves (e, perm order)
    __half* enh = ep + eh;                              // eh halves (en, perm order)
    int* counts    = (int*)(enh + eh);
    int* offsets   = counts + N;
    int* cursor    = offsets + N;
    int* blocksums = cursor + N;   // 128
    int* perm      = blocksums + 128;
    int* srcp      = perm + E;
    int* dstp      = srcp + E;

    size_t nh4 = nh / 4, eh4 = eh / 4;
    int gh4 = (int)((nh4 + 255) / 256);
    int ge4 = (int)((eh4 + 255) / 256);
    int gN = (N + 255) / 256;
    int gE = (E + 255) / 256;
    int nb = (N + 1023) / 1024;
    int ntileN = (N + 15) / 16;
    int gGemm = (ntileN + 3) / 4;
    if (gGemm > GRID_STRIDE) gGemm = GRID_STRIDE;

    // ---- CSR build (dst-sorted edge permutation) ----
    zero_ints<<<gN, 256, 0, stream>>>(counts, N);
    hist_kernel<<<gE, 256, 0, stream>>>(dsts, counts, E);
    scan1<<<nb, 256, 0, stream>>>(counts, offsets, blocksums, N);
    scan2<<<1, 64, 0, stream>>>(blocksums, nb);
    scan3<<<gN, 256, 0, stream>>>(offsets, blocksums, cursor, N);
    scatter_perm<<<GRID_STRIDE, 256, 0, stream>>>(dsts, cursor, perm, E, N);
    gather_sd<<<gE, 256, 0, stream>>>(perm, srcs, dsts, srcp, dstp, E);

    // ---- input projections ----
    init_proj4<<<gh4, 256, 0, stream>>>(x, pe_w, pe_b, (float4*)h, nh4);
    init_ep16<<<ge4, 256, 0, stream>>>(e_in, perm, ed_w, ed_b, (__half2*)ep, eh4);

    for (int l = 0; l < NLAYERS; l++) {
        if (l == 0)
            node_gemm<0><<<gGemm, 256, 0, stream>>>(h, hnew, stats + 0, stats + 32,
                Aw + l * 1024, Ab + l * 32, Bw + l * 1024, Bb + l * 32,
                Uw + l * 1024, Ub + l * 32, Vw + l * 1024, Vb + l * 32,
                Ah, Bh, Uh, Vh, N);
        else
            node_gemm<1><<<gGemm, 256, 0, stream>>>(h, hnew, stats + 0, stats + 32,
                Aw + l * 1024, Ab + l * 32, Bw + l * 1024, Bb + l * 32,
                Uw + l * 1024, Ub + l * 32, Vw + l * 1024, Vb + l * 32,
                Ah, Bh, Uh, Vh, N);
        if (l == 0)
            edge_layer<1><<<nbE, 256, 0, stream>>>(ep, enh, srcp, dstp, offsets, counts,
                Ah, Bh, Vh, Uh, hnew, Cw + l * 1024, Cb + l * 32,
                stats + 64, stats + 96, partial_e, partial_h, N, E);
        else
            edge_layer<0><<<nbE, 256, 0, stream>>>(ep, enh, srcp, dstp, offsets, counts,
                Ah, Bh, Vh, Uh, hnew, Cw + l * 1024, Cb + l * 32,
                stats + 64, stats + 96, partial_e, partial_h, N, E);
        stats_both<<<64, 256, 0, stream>>>(partial_e, partial_h, nbE,
            (double)E, (double)N,
            bn_e_g + l * 32, bn_e_b + l * 32, bn_h_g + l * 32, bn_h_b + l * 32, stats);
    }

    // final h-update straight to fp16 (Ah already consumed by edge_layer l=3)
    apply4_h16<<<gh4, 256, 0, stream>>>((const float4*)hnew, stats + 0, stats + 32,
                                        (const float4*)h, (__half2*)Ah, nh4);

    // predictor applies the deferred layer-3 e-update inline
    predictor<<<GRID_STRIDE, 256, 0, stream>>>((const __half*)Ah, ep, enh,
                                               srcp, dstp, perm, stats + 64, stats + 96,
                                               W1w, W1b, W2w, W2b,
                                               (float*)d_out, E);
}

// Round 9
// 652.704 us; speedup vs baseline: 1.0590x; 1.0590x over previous
//
#include <hip/hip_runtime.h>
#include <hip/hip_bf16.h>
#include <hip/hip_fp16.h>

#define NLAYERS 4
#define GRID_STRIDE 2048
#define NB 32          // nodes per edge_layer block
#define CAP 256        // LDS-resident edges per block (mean load; overflow -> global fallback)

typedef _Float16 half8_t __attribute__((ext_vector_type(8)));
typedef float float4_t __attribute__((ext_vector_type(4)));
typedef float float8_t __attribute__((ext_vector_type(8)));
typedef unsigned uint2_t __attribute__((ext_vector_type(2)));

// Global hidden-dim permutation: column pair (j, j+16) lives at positions (2j, 2j+1).
__device__ __forceinline__ int permcol(int pos) { return (pos >> 1) | ((pos & 1) << 4); }

__device__ __forceinline__ void unp4v(uint2_t r, float* f)
{
    unsigned lo = r.x, hi = r.y;
    float2 a = __half22float2(*(__half2*)&lo);
    float2 b = __half22float2(*(__half2*)&hi);
    f[0] = a.x; f[1] = a.y; f[2] = b.x; f[3] = b.y;
}

__device__ __forceinline__ float fast_sigmoid(float x)
{
    return __builtin_amdgcn_rcpf(1.f + __expf(-x));
}

// ---------------- small zero kernel ----------------
__global__ void zero_ints(int* __restrict__ p, int n)
{
    int i = blockIdx.x * 256 + threadIdx.x;
    if (i < n) p[i] = 0;
}

// ---------------- CSR build ----------------
__global__ void hist_kernel(const int* __restrict__ dsts, int* __restrict__ counts, int E)
{
    int i = blockIdx.x * 256 + threadIdx.x;
    if (i < E) atomicAdd(&counts[dsts[i]], 1);
}

__global__ __launch_bounds__(256) void scan1(const int* __restrict__ counts,
                                             int* __restrict__ offsets,
                                             int* __restrict__ blocksums, int N)
{
    __shared__ int sdata[256];
    int t = threadIdx.x;
    int bbase = blockIdx.x * 1024;
    int v[4]; int s = 0;
#pragma unroll
    for (int q = 0; q < 4; q++) {
        int idx = bbase + t * 4 + q;
        v[q] = (idx < N) ? counts[idx] : 0;
        s += v[q];
    }
    sdata[t] = s;
    __syncthreads();
    for (int off = 1; off < 256; off <<= 1) {
        int x = (t >= off) ? sdata[t - off] : 0;
        __syncthreads();
        sdata[t] += x;
        __syncthreads();
    }
    int excl = sdata[t] - s;
    int run = excl;
#pragma unroll
    for (int q = 0; q < 4; q++) {
        int idx = bbase + t * 4 + q;
        if (idx < N) offsets[idx] = run;
        run += v[q];
    }
    if (t == 255) blocksums[blockIdx.x] = sdata[255];
}

__global__ void scan2(int* __restrict__ blocksums, int nb)
{
    if (threadIdx.x == 0 && blockIdx.x == 0) {
        int run = 0;
        for (int b = 0; b < nb; b++) { int t = blocksums[b]; blocksums[b] = run; run += t; }
    }
}

__global__ void scan3(int* __restrict__ offsets, const int* __restrict__ blocksums,
                      int* __restrict__ cursor, int N)
{
    int i = blockIdx.x * 256 + threadIdx.x;
    if (i < N) {
        int v = offsets[i] + blocksums[i >> 10];
        offsets[i] = v;
        cursor[i] = v;
    }
}

// scatter: 8 dst-range groups (XCD-affine via blockIdx&7).
__global__ void scatter_perm(const int* __restrict__ dsts, int* __restrict__ cursor,
                             int* __restrict__ perm, int E, int N)
{
    int g = blockIdx.x & 7;
    int lo = (int)((long long)N * g >> 3);
    int hi = (int)((long long)N * (g + 1) >> 3);
    int nbg = gridDim.x >> 3;
    int bg = blockIdx.x >> 3;
    for (int i = bg * 256 + threadIdx.x; i < E; i += nbg * 256) {
        int d = dsts[i];
        if (d >= lo && d < hi) {
            int slot = atomicAdd(&cursor[d], 1);
            perm[slot] = i;
        }
    }
}

__global__ void gather_sd(const int* __restrict__ perm, const int* __restrict__ srcs,
                          const int* __restrict__ dsts, int* __restrict__ srcp,
                          int* __restrict__ dstp, int E)
{
    int i = blockIdx.x * 256 + threadIdx.x;
    if (i < E) {
        int e = perm[i];
        srcp[i] = srcs[e];
        dstp[i] = dsts[e];
    }
}

// ---------------- init projections (write POSITION space) ----------------
__global__ void init_proj4(const float* __restrict__ in, const float* __restrict__ w,
                           const float* __restrict__ b, float4* __restrict__ out, size_t n4)
{
    size_t i = (size_t)blockIdx.x * 256 + threadIdx.x;
    if (i < n4) {
        int j4 = (int)(i & 7) * 4;
        float xv = in[i >> 3];
        int c0 = permcol(j4), c1 = permcol(j4 + 1), c2 = permcol(j4 + 2), c3 = permcol(j4 + 3);
        out[i] = make_float4(fmaf(xv, w[c0], b[c0]), fmaf(xv, w[c1], b[c1]),
                             fmaf(xv, w[c2], b[c2]), fmaf(xv, w[c3], b[c3]));
    }
}

__global__ void init_ep16(const float* __restrict__ e_in, const int* __restrict__ perm,
                          const float* __restrict__ w, const float* __restrict__ b,
                          __half2* __restrict__ out, size_t n4)
{
    size_t i = (size_t)blockIdx.x * 256 + threadIdx.x;
    if (i < n4) {
        int row = (int)(i >> 3);
        float xv = e_in[perm[row]];
        int j4 = (int)(i & 7) * 4;
        int c0 = permcol(j4), c1 = permcol(j4 + 1), c2 = permcol(j4 + 2), c3 = permcol(j4 + 3);
        out[i * 2]     = __floats2half2_rn(fmaf(xv, w[c0], b[c0]), fmaf(xv, w[c1], b[c1]));
        out[i * 2 + 1] = __floats2half2_rn(fmaf(xv, w[c2], b[c2]), fmaf(xv, w[c3], b[c3]));
    }
}

// ---- node GEMMs (MFMA): 16-node tile per wave; weight rows permuted; outputs pairwise.
template <int FUSE>
__global__ __launch_bounds__(256) void node_gemm(
    float* __restrict__ h, const float* __restrict__ hnew_in,
    const float* __restrict__ sc_h, const float* __restrict__ sh_h,
    const float* __restrict__ Aw, const float* __restrict__ Ab,
    const float* __restrict__ Bw, const float* __restrict__ Bb,
    const float* __restrict__ Uw, const float* __restrict__ Ub,
    const float* __restrict__ Vw, const float* __restrict__ Vb,
    __half* __restrict__ Ahh, __half* __restrict__ Bhh,
    __half* __restrict__ Uhh, __half* __restrict__ Vhh, int N)
{
    int tid = threadIdx.x;
    int lane = tid & 63;
    int m = lane & 15, q = lane >> 4;
    half8_t bA0, bA1, bB0, bB1, bU0, bU1, bV0, bV1;
    float scq[8], shq[8];
#pragma unroll
    for (int i = 0; i < 8; i++) {
        int k = q * 8 + i;       // position index
        int kr = permcol(k);     // original weight row
        bA0[i] = (_Float16)Aw[kr * 32 + m];  bA1[i] = (_Float16)Aw[kr * 32 + m + 16];
        bB0[i] = (_Float16)Bw[kr * 32 + m];  bB1[i] = (_Float16)Bw[kr * 32 + m + 16];
        bU0[i] = (_Float16)Uw[kr * 32 + m];  bU1[i] = (_Float16)Uw[kr * 32 + m + 16];
        bV0[i] = (_Float16)Vw[kr * 32 + m];  bV1[i] = (_Float16)Vw[kr * 32 + m + 16];
        if (FUSE) { scq[i] = sc_h[k]; shq[i] = sh_h[k]; }   // position-indexed stats
    }
    float ab0 = Ab[m], ab1 = Ab[m + 16];
    float bb0 = Bb[m], bb1 = Bb[m + 16];
    float ub0 = Ub[m], ub1 = Ub[m + 16];
    float vb0 = Vb[m], vb1 = Vb[m + 16];

    int ntile = (N + 15) >> 4;
    int wid = blockIdx.x * 4 + (tid >> 6);
    int nwave = gridDim.x * 4;
    for (int t = wid; t < ntile; t += nwave) {
        int base = t << 4;
        int arow = base + m;
        bool valid = arow < N;
        if (!valid) arow = N - 1;
        float8_t hv = *(const float8_t*)(h + (size_t)arow * 32 + q * 8);
        if (FUSE) {
            float8_t pv = *(const float8_t*)(hnew_in + (size_t)arow * 32 + q * 8);
#pragma unroll
            for (int i = 0; i < 8; i++)
                hv[i] += fmaxf(fmaf(pv[i], scq[i], shq[i]), 0.f);
            if (valid) *(float8_t*)(h + (size_t)arow * 32 + q * 8) = hv;
        }
        half8_t a;
#pragma unroll
        for (int i = 0; i < 8; i++) a[i] = (_Float16)hv[i];
        float4_t aA0 = __builtin_amdgcn_mfma_f32_16x16x32_f16(a, bA0, (float4_t){0,0,0,0}, 0, 0, 0);
        float4_t aA1 = __builtin_amdgcn_mfma_f32_16x16x32_f16(a, bA1, (float4_t){0,0,0,0}, 0, 0, 0);
        float4_t aB0 = __builtin_amdgcn_mfma_f32_16x16x32_f16(a, bB0, (float4_t){0,0,0,0}, 0, 0, 0);
        float4_t aB1 = __builtin_amdgcn_mfma_f32_16x16x32_f16(a, bB1, (float4_t){0,0,0,0}, 0, 0, 0);
        float4_t aU0 = __builtin_amdgcn_mfma_f32_16x16x32_f16(a, bU0, (float4_t){0,0,0,0}, 0, 0, 0);
        float4_t aU1 = __builtin_amdgcn_mfma_f32_16x16x32_f16(a, bU1, (float4_t){0,0,0,0}, 0, 0, 0);
        float4_t aV0 = __builtin_amdgcn_mfma_f32_16x16x32_f16(a, bV0, (float4_t){0,0,0,0}, 0, 0, 0);
        float4_t aV1 = __builtin_amdgcn_mfma_f32_16x16x32_f16(a, bV1, (float4_t){0,0,0,0}, 0, 0, 0);
#pragma unroll
        for (int reg = 0; reg < 4; reg++) {
            int node = base + q * 4 + reg;
            if (node < N) {
                size_t o = (size_t)node * 32;
                *(__half2*)(Ahh + o + 2 * m) = __floats2half2_rn(aA0[reg] + ab0, aA1[reg] + ab1);
                *(__half2*)(Bhh + o + 2 * m) = __floats2half2_rn(aB0[reg] + bb0, aB1[reg] + bb1);
                *(__half2*)(Vhh + o + 2 * m) = __floats2half2_rn(aV0[reg] + vb0, aV1[reg] + vb1);
                *(__half2*)(Uhh + o + 2 * m) = __floats2half2_rn(aU0[reg] + ub0, aU1[reg] + ub1);
            }
        }
    }
}

// ---- fused per-layer edge kernel. Phase 1 is 2-tile software-pipelined: each wave
// processes tiles (t, t+4) per iteration, issuing BOTH tiles' ep/enh/idx loads and all
// Ah/Bh gathers before either MFMA -> 2x outstanding requests per wave (MLP fix).
template <int FIRST>
__global__ __launch_bounds__(256) void edge_layer(
    __half* __restrict__ ep, __half* __restrict__ enh,
    const int* __restrict__ srcp, const int* __restrict__ dstp,
    const int* __restrict__ offsets, const int* __restrict__ counts,
    const __half* __restrict__ Ah, const __half* __restrict__ Bh,
    const __half* __restrict__ Vh, const __half* __restrict__ Uh,
    float* __restrict__ hnew,
    const float* __restrict__ Cw, const float* __restrict__ Cb,
    const float* __restrict__ sc_e, const float* __restrict__ sh_e,
    float* __restrict__ partial_e, float* __restrict__ partial_h,
    int N, int E)
{
    __shared__ __half en_lds[CAP * 32];   // 16384 B
    __shared__ int src_lds[CAP];          // 1024 B
    __shared__ float red[512];            // 2048 B  -> 19456 B total

    int tid = threadIdx.x;
    int lane = tid & 63;
    int m = lane & 15, q = lane >> 4;

    int n0 = blockIdx.x * NB;
    int n1 = n0 + NB; if (n1 > N) n1 = N;
    int e0 = offsets[n0];
    int e1 = (n1 < N) ? offsets[n1] : E;

    // ---------------- phase 1: en compute (2-tile pipelined) ----------------
    half8_t b0, b1;
    float sca[8], sha[8];
#pragma unroll
    for (int i = 0; i < 8; i++) {
        int k = q * 8 + i;
        int kr = permcol(k);
        b0[i] = (_Float16)Cw[kr * 32 + m];
        b1[i] = (_Float16)Cw[kr * 32 + m + 16];
        if (!FIRST) { sca[i] = sc_e[k]; sha[i] = sh_e[k]; }
    }
    float cb0 = Cb[m], cb1 = Cb[m + 16];
    float es0 = 0.f, eq0 = 0.f, es1 = 0.f, eq1 = 0.f;

    int len = e1 - e0;
    int T = (len + 15) >> 4;
    int w = tid >> 6;
    for (int t = w; t < T; t += 8) {
        int tB = t + 4;
        bool hasB = (tB < T);

        // ---- tile A loads ----
        int ebA = e0 + (t << 4);
        int arA = ebA + m;
        bool avA = arA < e1;
        int arAc = avA ? arA : e1 - 1;
        half8_t aA = *(const half8_t*)(ep + (size_t)arAc * 32 + q * 8);
        half8_t enpA;
        if (!FIRST) enpA = *(const half8_t*)(enh + (size_t)arAc * 32 + q * 8);
        int sA[4], dA[4];
#pragma unroll
        for (int reg = 0; reg < 4; reg++) {
            int e = ebA + q * 4 + reg; if (e >= e1) e = e1 - 1;
            sA[reg] = srcp[e]; dA[reg] = dstp[e];
        }

        // ---- tile B loads (dummy = last edge when absent) ----
        int ebB = e0 + (tB << 4);
        int arB = ebB + m;
        bool avB = hasB && (arB < e1);
        int arBc = avB ? arB : e1 - 1;
        half8_t aB = *(const half8_t*)(ep + (size_t)arBc * 32 + q * 8);
        half8_t enpB;
        if (!FIRST) enpB = *(const half8_t*)(enh + (size_t)arBc * 32 + q * 8);
        int sB[4], dB[4];
#pragma unroll
        for (int reg = 0; reg < 4; reg++) {
            int e = ebB + q * 4 + reg; if (!hasB || e >= e1) e = e1 - 1;
            sB[reg] = srcp[e]; dB[reg] = dstp[e];
        }

        // ---- all gathers issued before MFMAs ----
        __half2 ahA[4], bhA[4], ahB[4], bhB[4];
#pragma unroll
        for (int reg = 0; reg < 4; reg++) {
            ahA[reg] = *(const __half2*)(Ah + (size_t)dA[reg] * 32 + 2 * m);
            bhA[reg] = *(const __half2*)(Bh + (size_t)sA[reg] * 32 + 2 * m);
            ahB[reg] = *(const __half2*)(Ah + (size_t)dB[reg] * 32 + 2 * m);
            bhB[reg] = *(const __half2*)(Bh + (size_t)sB[reg] * 32 + 2 * m);
        }

        // ---- deferred e-apply + ep writeback (both tiles) ----
        if (!FIRST) {
#pragma unroll
            for (int i = 0; i < 8; i++) {
                aA[i] = (_Float16)((float)aA[i] + fmaxf(fmaf((float)enpA[i], sca[i], sha[i]), 0.f));
                aB[i] = (_Float16)((float)aB[i] + fmaxf(fmaf((float)enpB[i], sca[i], sha[i]), 0.f));
            }
            if (avA) *(half8_t*)(ep + (size_t)arA * 32 + q * 8) = aA;
            if (avB) *(half8_t*)(ep + (size_t)arB * 32 + q * 8) = aB;
        }

        // ---- MFMAs (back to back; independent) ----
        float4_t accA0 = __builtin_amdgcn_mfma_f32_16x16x32_f16(aA, b0, (float4_t){0.f,0.f,0.f,0.f}, 0, 0, 0);
        float4_t accA1 = __builtin_amdgcn_mfma_f32_16x16x32_f16(aA, b1, (float4_t){0.f,0.f,0.f,0.f}, 0, 0, 0);
        float4_t accB0 = __builtin_amdgcn_mfma_f32_16x16x32_f16(aB, b0, (float4_t){0.f,0.f,0.f,0.f}, 0, 0, 0);
        float4_t accB1 = __builtin_amdgcn_mfma_f32_16x16x32_f16(aB, b1, (float4_t){0.f,0.f,0.f,0.f}, 0, 0, 0);

        // ---- epilogue A ----
#pragma unroll
        for (int reg = 0; reg < 4; reg++) {
            int edge = ebA + q * 4 + reg;
            if (edge < e1) {
                float2 ah = __half22float2(ahA[reg]);
                float2 bh = __half22float2(bhA[reg]);
                float en0 = accA0[reg] + cb0 + ah.x + bh.x;
                float en1 = accA1[reg] + cb1 + ah.y + bh.y;
                __half2 env = __floats2half2_rn(en0, en1);
                *(__half2*)(enh + (size_t)edge * 32 + 2 * m) = env;
                int le = edge - e0;
                if (le < CAP) {
                    *(__half2*)(en_lds + le * 32 + 2 * m) = env;
                    if (m == 0) src_lds[le] = sA[reg];
                }
                es0 += en0; eq0 += en0 * en0;
                es1 += en1; eq1 += en1 * en1;
            }
        }
        // ---- epilogue B ----
        if (hasB) {
#pragma unroll
            for (int reg = 0; reg < 4; reg++) {
                int edge = ebB + q * 4 + reg;
                if (edge < e1) {
                    float2 ah = __half22float2(ahB[reg]);
                    float2 bh = __half22float2(bhB[reg]);
                    float en0 = accB0[reg] + cb0 + ah.x + bh.x;
                    float en1 = accB1[reg] + cb1 + ah.y + bh.y;
                    __half2 env = __floats2half2_rn(en0, en1);
                    *(__half2*)(enh + (size_t)edge * 32 + 2 * m) = env;
                    int le = edge - e0;
                    if (le < CAP) {
                        *(__half2*)(en_lds + le * 32 + 2 * m) = env;
                        if (m == 0) src_lds[le] = sB[reg];
                    }
                    es0 += en0; eq0 += en0 * en0;
                    es1 += en1; eq1 += en1 * en1;
                }
            }
        }
    }

    // e-stats reduction by POSITION (es0 -> pos 2m, es1 -> pos 2m+1)
    float* pe = partial_e + (size_t)blockIdx.x * 64;
    __syncthreads();
    red[tid] = es0;
    __syncthreads();
    if (tid < 16) {
        float s = 0.f;
#pragma unroll
        for (int ww = 0; ww < 4; ww++)
#pragma unroll
            for (int k = 0; k < 4; k++) s += red[ww * 64 + k * 16 + tid];
        pe[2 * tid] = s;
    }
    __syncthreads();
    red[tid] = es1;
    __syncthreads();
    if (tid < 16) {
        float s = 0.f;
#pragma unroll
        for (int ww = 0; ww < 4; ww++)
#pragma unroll
            for (int k = 0; k < 4; k++) s += red[ww * 64 + k * 16 + tid];
        pe[2 * tid + 1] = s;
    }
    __syncthreads();
    red[tid] = eq0;
    __syncthreads();
    if (tid < 16) {
        float s = 0.f;
#pragma unroll
        for (int ww = 0; ww < 4; ww++)
#pragma unroll
            for (int k = 0; k < 4; k++) s += red[ww * 64 + k * 16 + tid];
        pe[32 + 2 * tid] = s;
    }
    __syncthreads();
    red[tid] = eq1;
    __syncthreads();
    if (tid < 16) {
        float s = 0.f;
#pragma unroll
        for (int ww = 0; ww < 4; ww++)
#pragma unroll
            for (int k = 0; k < 4; k++) s += red[ww * 64 + k * 16 + tid];
        pe[32 + 2 * tid + 1] = s;
    }

    // ---------------- phase 2: per-node aggregation from LDS ----------------
    int u = tid & 7, grp = tid >> 3;      // 32 groups of 8 lanes; 1 node each
    int c0 = 4 * u;                       // positions c0..c0+3
    float hs[4] = {0.f, 0.f, 0.f, 0.f}, hq[4] = {0.f, 0.f, 0.f, 0.f};

    int n = n0 + grp;
    if (n < N) {
        int start = offsets[n], lenn = counts[n];
        int lb = start - e0;
        int inl = CAP - lb; if (inl < 0) inl = 0; if (inl > lenn) inl = lenn;
        float num[4] = {0.f, 0.f, 0.f, 0.f}, den[4] = {0.f, 0.f, 0.f, 0.f};
        int qq = 0;
        for (; qq + 2 <= inl; qq += 2) {
            int le0 = lb + qq, le1 = le0 + 1;
            int s0 = src_lds[le0], s1 = src_lds[le1];
            uint2_t enr0 = *(const uint2_t*)(en_lds + le0 * 32 + c0);
            uint2_t enr1 = *(const uint2_t*)(en_lds + le1 * 32 + c0);
            uint2_t vhr0 = *(const uint2_t*)(Vh + (size_t)s0 * 32 + c0);
            uint2_t vhr1 = *(const uint2_t*)(Vh + (size_t)s1 * 32 + c0);
            float en0[4], en1[4], vh0[4], vh1[4];
            unp4v(enr0, en0); unp4v(enr1, en1);
            unp4v(vhr0, vh0); unp4v(vhr1, vh1);
#pragma unroll
            for (int k = 0; k < 4; k++) {
                float sg0 = fast_sigmoid(en0[k]);
                float sg1 = fast_sigmoid(en1[k]);
                num[k] = fmaf(sg0, vh0[k], num[k]);
                num[k] = fmaf(sg1, vh1[k], num[k]);
                den[k] += sg0 + sg1;
            }
        }
        if (qq < inl) {
            int le0 = lb + qq;
            int s0 = src_lds[le0];
            uint2_t enr0 = *(const uint2_t*)(en_lds + le0 * 32 + c0);
            uint2_t vhr0 = *(const uint2_t*)(Vh + (size_t)s0 * 32 + c0);
            float en0[4], vh0[4];
            unp4v(enr0, en0); unp4v(vhr0, vh0);
#pragma unroll
            for (int k = 0; k < 4; k++) {
                float sg0 = fast_sigmoid(en0[k]);
                num[k] = fmaf(sg0, vh0[k], num[k]);
                den[k] += sg0;
            }
            qq++;
        }
        for (; qq < lenn; qq++) {         // overflow fallback (rare)
            int ge = start + qq;
            int s0 = srcp[ge];
            uint2_t enr0 = *(const uint2_t*)(enh + (size_t)ge * 32 + c0);
            uint2_t vhr0 = *(const uint2_t*)(Vh + (size_t)s0 * 32 + c0);
            float en0[4], vh0[4];
            unp4v(enr0, en0); unp4v(vhr0, vh0);
#pragma unroll
            for (int k = 0; k < 4; k++) {
                float sg0 = fast_sigmoid(en0[k]);
                num[k] = fmaf(sg0, vh0[k], num[k]);
                den[k] += sg0;
            }
        }
        size_t ho = (size_t)n * 32 + c0;
        uint2_t uhr = *(const uint2_t*)(Uh + ho);
        float uh[4];
        unp4v(uhr, uh);
        float hv[4];
#pragma unroll
        for (int k = 0; k < 4; k++)
            hv[k] = uh[k] + num[k] * __builtin_amdgcn_rcpf(den[k] + 1e-6f);
        *(float4*)(hnew + ho) = make_float4(hv[0], hv[1], hv[2], hv[3]);
#pragma unroll
        for (int k = 0; k < 4; k++) { hs[k] += hv[k]; hq[k] += hv[k] * hv[k]; }
    }

    // h-stats reduction
    float* ph = partial_h + (size_t)blockIdx.x * 64;
#pragma unroll
    for (int k = 0; k < 4; k++) {
        __syncthreads();
        red[tid] = hs[k]; red[256 + tid] = hq[k];
        __syncthreads();
        if (tid < 8) {
            float s = 0.f;
#pragma unroll
            for (int g = 0; g < 32; g++) s += red[g * 8 + tid];
            ph[4 * tid + k] = s;
        } else if (tid < 16) {
            int uu = tid - 8;
            float s = 0.f;
#pragma unroll
            for (int g = 0; g < 32; g++) s += red[256 + g * 8 + uu];
            ph[32 + 4 * uu + k] = s;
        }
    }
}

// ---- finalize BN stats BOTH sides in one launch: 64 blocks (0-31 e, 32-63 h) ----
__global__ __launch_bounds__(256) void stats_both(
    const float* __restrict__ pe, const float* __restrict__ ph, int nrows,
    double cntE, double cntN,
    const float* __restrict__ eg, const float* __restrict__ eb,
    const float* __restrict__ hg, const float* __restrict__ hb,
    float* __restrict__ stats)
{
    int j = blockIdx.x;
    int side = j >> 5, jj = j & 31;           // side 0 = e, 1 = h; jj = position
    int col = (jj >> 1) | ((jj & 1) << 4);    // original column for g/b lookup
    const float* partial = side ? ph : pe;
    __shared__ double rs[256], rq[256];
    double s = 0.0, q = 0.0;
    for (int r = threadIdx.x; r < nrows; r += 256) {
        s += (double)partial[(size_t)r * 64 + jj];
        q += (double)partial[(size_t)r * 64 + 32 + jj];
    }
    rs[threadIdx.x] = s; rq[threadIdx.x] = q;
    __syncthreads();
    for (int off = 128; off; off >>= 1) {
        if (threadIdx.x < off) { rs[threadIdx.x] += rs[threadIdx.x + off]; rq[threadIdx.x] += rq[threadIdx.x + off]; }
        __syncthreads();
    }
    if (threadIdx.x == 0) {
        double cnt = side ? cntN : cntE;
        double mean = rs[0] / cnt;
        double var = rq[0] / cnt - mean * mean;
        const float* g = side ? hg : eg;
        const float* b = side ? hb : eb;
        float scale = g[col] * (float)(1.0 / sqrt(var + 1e-5));
        int off2 = side ? 0 : 64;   // h -> stats[0/32], e -> stats[64/96]
        stats[off2 + jj] = scale;
        stats[off2 + 32 + jj] = b[col] - (float)mean * scale;
    }
}

// ---- final h apply: h16 = fp16(h + relu(hnew*sc+sh)) ----
__global__ void apply4_h16(const float4* __restrict__ pre, const float* __restrict__ scale,
                           const float* __restrict__ shift, const float4* __restrict__ hold,
                           __half2* __restrict__ h16, size_t n4)
{
    size_t i = (size_t)blockIdx.x * 256 + threadIdx.x;
    if (i < n4) {
        int j4 = (int)(i & 7) * 4;
        float4 sc = *(const float4*)(scale + j4);
        float4 sh = *(const float4*)(shift + j4);
        float4 p = pre[i], a = hold[i];
        a.x += fmaxf(fmaf(p.x, sc.x, sh.x), 0.f);
        a.y += fmaxf(fmaf(p.y, sc.y, sh.y), 0.f);
        a.z += fmaxf(fmaf(p.z, sc.z, sh.z), 0.f);
        a.w += fmaxf(fmaf(p.w, sc.w, sh.w), 0.f);
        h16[i * 2]     = __floats2half2_rn(a.x, a.y);
        h16[i * 2 + 1] = __floats2half2_rn(a.z, a.w);
    }
}

// ---- predictor (MFMA), PERM edge order; fuses the deferred layer-3 e-apply ----
__global__ __launch_bounds__(256) void predictor(
    const __half* __restrict__ h16, const __half* __restrict__ ep,
    const __half* __restrict__ enh,
    const int* __restrict__ srcp, const int* __restrict__ dstp, const int* __restrict__ perm,
    const float* __restrict__ sc_e, const float* __restrict__ sh_e,
    const float* __restrict__ W1, const float* __restrict__ b1,
    const float* __restrict__ W2, const float* __restrict__ b2v,
    float* __restrict__ out, int E)
{
    int tid = threadIdx.x;
    int lane = tid & 63;
    int m = lane & 15, q = lane >> 4;
    half8_t bf00, bf01, bf10, bf11, bf20, bf21;
    float scq[8], shq[8];
#pragma unroll
    for (int i = 0; i < 8; i++) {
        int k = q * 8 + i;
        int kr = permcol(k);
        bf00[i] = (_Float16)W1[kr * 32 + m];
        bf01[i] = (_Float16)W1[kr * 32 + m + 16];
        bf10[i] = (_Float16)W1[(32 + kr) * 32 + m];
        bf11[i] = (_Float16)W1[(32 + kr) * 32 + m + 16];
        bf20[i] = (_Float16)W1[(64 + kr) * 32 + m];
        bf21[i] = (_Float16)W1[(64 + kr) * 32 + m + 16];
        scq[i] = sc_e[k]; shq[i] = sh_e[k];
    }
    float b10 = b1[m], b11 = b1[m + 16];
    float w20 = W2[m], w21 = W2[m + 16];
    float b2 = b2v[0];

    int ntile = (E + 15) >> 4;
    int wid = blockIdx.x * 4 + (tid >> 6);
    int nwave = gridDim.x * 4;
    for (int t = wid; t < ntile; t += nwave) {
        int base = t << 4;
        int arow = base + m;
        if (arow >= E) arow = E - 1;
        int s = srcp[arow], d = dstp[arow];
        half8_t a0 = *(const half8_t*)(h16 + (size_t)s * 32 + q * 8);
        half8_t a1 = *(const half8_t*)(h16 + (size_t)d * 32 + q * 8);
        half8_t ee = *(const half8_t*)(ep + (size_t)arow * 32 + q * 8);
        half8_t enr = *(const half8_t*)(enh + (size_t)arow * 32 + q * 8);
        half8_t a2;
#pragma unroll
        for (int i = 0; i < 8; i++) {
            float evv = (float)ee[i] + fmaxf(fmaf((float)enr[i], scq[i], shq[i]), 0.f);
            a2[i] = (_Float16)evv;
        }
        float4_t acc0 = {0.f, 0.f, 0.f, 0.f}, acc1 = {0.f, 0.f, 0.f, 0.f};
        acc0 = __builtin_amdgcn_mfma_f32_16x16x32_f16(a0, bf00, acc0, 0, 0, 0);
        acc1 = __builtin_amdgcn_mfma_f32_16x16x32_f16(a0, bf01, acc1, 0, 0, 0);
        acc0 = __builtin_amdgcn_mfma_f32_16x16x32_f16(a1, bf10, acc0, 0, 0, 0);
        acc1 = __builtin_amdgcn_mfma_f32_16x16x32_f16(a1, bf11, acc1, 0, 0, 0);
        acc0 = __builtin_amdgcn_mfma_f32_16x16x32_f16(a2, bf20, acc0, 0, 0, 0);
        acc1 = __builtin_amdgcn_mfma_f32_16x16x32_f16(a2, bf21, acc1, 0, 0, 0);
#pragma unroll
        for (int reg = 0; reg < 4; reg++) {
            float tp = fmaxf(acc0[reg] + b10, 0.f) * w20
                     + fmaxf(acc1[reg] + b11, 0.f) * w21;
            tp += __shfl_xor(tp, 1);
            tp += __shfl_xor(tp, 2);
            tp += __shfl_xor(tp, 4);
            tp += __shfl_xor(tp, 8);
            int idx = base + q * 4 + reg;
            if (m == 0 && idx < E) {
                int oe = perm[idx];
                out[oe] = tp + b2;
            }
        }
    }
}

extern "C" void kernel_launch(void* const* d_in, const int* in_sizes, int n_in,
                              void* d_out, int out_size, void* d_ws, size_t ws_size,
                              hipStream_t stream)
{
    const int N = in_sizes[0];
    const int E = in_sizes[1];

    const float* x    = (const float*)d_in[0];
    const float* e_in = (const float*)d_in[1];
    const int*   eidx = (const int*)d_in[2];
    const float* pe_w = (const float*)d_in[3];
    const float* pe_b = (const float*)d_in[4];
    const float* ed_w = (const float*)d_in[5];
    const float* ed_b = (const float*)d_in[6];
    const float* Aw = (const float*)d_in[7];
    const float* Ab = (const float*)d_in[8];
    const float* Bw = (const float*)d_in[9];
    const float* Bb = (const float*)d_in[10];
    const float* Cw = (const float*)d_in[11];
    const float* Cb = (const float*)d_in[12];
    const float* Uw = (const float*)d_in[13];
    const float* Ub = (const float*)d_in[14];
    const float* Vw = (const float*)d_in[15];
    const float* Vb = (const float*)d_in[16];
    const float* bn_h_g = (const float*)d_in[17];
    const float* bn_h_b = (const float*)d_in[18];
    const float* bn_e_g = (const float*)d_in[19];
    const float* bn_e_b = (const float*)d_in[20];
    const float* W1w = (const float*)d_in[21];
    const float* W1b = (const float*)d_in[22];
    const float* W2w = (const float*)d_in[23];
    const float* W2b = (const float*)d_in[24];

    const int* srcs = eidx;
    const int* dsts = eidx + E;

    size_t nh = (size_t)N * 32;
    size_t eh = (size_t)E * 32;
    int nbE = (N + NB - 1) / NB;    // edge_layer grid

    float* ws = (float*)d_ws;
    float* stats     = ws;                              // 128
    float* partial_e = stats + 128;                     // nbE*64
    float* partial_h = partial_e + (size_t)nbE * 64;    // nbE*64
    float* h    = partial_h + (size_t)nbE * 64;         // nh floats
    float* hnew = h + nh;                               // nh floats (h_new)
    __half* Ah  = (__half*)(hnew + nh);                 // nh halves (h16 at the end)
    __half* Bh  = Ah + nh;                              // nh halves
    __half* Vh  = Bh + nh;                              // nh halves
    __half* Uh  = Vh + nh;                              // nh halves (fp16 Uh)
    __half* ep  = Uh + nh;                              // eh halves (e, perm order)
    __half* enh = ep + eh;                              // eh halves (en, perm order)
    int* counts    = (int*)(enh + eh);
    int* offsets   = counts + N;
    int* cursor    = offsets + N;
    int* blocksums = cursor + N;   // 128
    int* perm      = blocksums + 128;
    int* srcp      = perm + E;
    int* dstp      = srcp + E;

    size_t nh4 = nh / 4, eh4 = eh / 4;
    int gh4 = (int)((nh4 + 255) / 256);
    int ge4 = (int)((eh4 + 255) / 256);
    int gN = (N + 255) / 256;
    int gE = (E + 255) / 256;
    int nb = (N + 1023) / 1024;
    int ntileN = (N + 15) / 16;
    int gGemm = (ntileN + 3) / 4;
    if (gGemm > GRID_STRIDE) gGemm = GRID_STRIDE;

    // ---- CSR build (dst-sorted edge permutation) ----
    zero_ints<<<gN, 256, 0, stream>>>(counts, N);
    hist_kernel<<<gE, 256, 0, stream>>>(dsts, counts, E);
    scan1<<<nb, 256, 0, stream>>>(counts, offsets, blocksums, N);
    scan2<<<1, 64, 0, stream>>>(blocksums, nb);
    scan3<<<gN, 256, 0, stream>>>(offsets, blocksums, cursor, N);
    scatter_perm<<<GRID_STRIDE, 256, 0, stream>>>(dsts, cursor, perm, E, N);
    gather_sd<<<gE, 256, 0, stream>>>(perm, srcs, dsts, srcp, dstp, E);

    // ---- input projections ----
    init_proj4<<<gh4, 256, 0, stream>>>(x, pe_w, pe_b, (float4*)h, nh4);
    init_ep16<<<ge4, 256, 0, stream>>>(e_in, perm, ed_w, ed_b, (__half2*)ep, eh4);

    for (int l = 0; l < NLAYERS; l++) {
        if (l == 0)
            node_gemm<0><<<gGemm, 256, 0, stream>>>(h, hnew, stats + 0, stats + 32,
                Aw + l * 1024, Ab + l * 32, Bw + l * 1024, Bb + l * 32,
                Uw + l * 1024, Ub + l * 32, Vw + l * 1024, Vb + l * 32,
                Ah, Bh, Uh, Vh, N);
        else
            node_gemm<1><<<gGemm, 256, 0, stream>>>(h, hnew, stats + 0, stats + 32,
                Aw + l * 1024, Ab + l * 32, Bw + l * 1024, Bb + l * 32,
                Uw + l * 1024, Ub + l * 32, Vw + l * 1024, Vb + l * 32,
                Ah, Bh, Uh, Vh, N);
        if (l == 0)
            edge_layer<1><<<nbE, 256, 0, stream>>>(ep, enh, srcp, dstp, offsets, counts,
                Ah, Bh, Vh, Uh, hnew, Cw + l * 1024, Cb + l * 32,
                stats + 64, stats + 96, partial_e, partial_h, N, E);
        else
            edge_layer<0><<<nbE, 256, 0, stream>>>(ep, enh, srcp, dstp, offsets, counts,
                Ah, Bh, Vh, Uh, hnew, Cw + l * 1024, Cb + l * 32,
                stats + 64, stats + 96, partial_e, partial_h, N, E);
        stats_both<<<64, 256, 0, stream>>>(partial_e, partial_h, nbE,
            (double)E, (double)N,
            bn_e_g + l * 32, bn_e_b + l * 32, bn_h_g + l * 32, bn_h_b + l * 32, stats);
    }

    // final h-update straight to fp16 (Ah already consumed by edge_layer l=3)
    apply4_h16<<<gh4, 256, 0, stream>>>((const float4*)hnew, stats + 0, stats + 32,
                                        (const float4*)h, (__half2*)Ah, nh4);

    // predictor applies the deferred layer-3 e-update inline
    predictor<<<GRID_STRIDE, 256, 0, stream>>>((const __half*)Ah, ep, enh,
                                               srcp, dstp, perm, stats + 64, stats + 96,
                                               W1w, W1b, W2w, W2b,
                                               (float*)d_out, E);
}